// Round 1
// baseline (649.438 us; speedup 1.0000x reference)
//
#include <hip/hip_runtime.h>

typedef _Float16 half_t;
typedef _Float16 h8 __attribute__((ext_vector_type(8)));
typedef _Float16 h4 __attribute__((ext_vector_type(4)));
typedef float f4 __attribute__((ext_vector_type(4)));

#define DEV __device__ __forceinline__

constexpr int Bc = 2, Sc = 4096, Ec = 1024, Hc = 16, Dc = 64, Wc = 256, Gc = 64;
constexpr int SLOTS = Gc + 3 * Wc;   // 832 key slots per query
constexpr int SCP = 836;             // padded LDS score row stride (floats), 16B aligned
constexpr float QSCALE = 0.125f;     // 1/sqrt(D)
constexpr float NEGV = -1e9f;

DEV f4 mfma16(h8 a, h8 b, f4 c) {
  return __builtin_amdgcn_mfma_f32_16x16x32_f16(a, b, c, 0, 0, 0);
}

DEV void gl_lds16(const half_t* g, half_t* l) {
  __builtin_amdgcn_global_load_lds((const __attribute__((address_space(1))) void*)g,
                                   (__attribute__((address_space(3))) void*)l, 16, 0, 0);
}

// ---------------- conversion kernels ----------------

__global__ void cvt_x_kernel(const float* __restrict__ x, half_t* __restrict__ xh) {
  int i = blockIdx.x * 256 + threadIdx.x;
  float4 v = ((const float4*)x)[i];
  h4 o;
  o[0] = (half_t)v.x; o[1] = (half_t)v.y; o[2] = (half_t)v.z; o[3] = (half_t)v.w;
  ((h4*)xh)[i] = o;
}

// W (K=1024 x N=1024 fp32) -> Wt (N x K f16)
__global__ void wcvt_kernel(const float* __restrict__ W, half_t* __restrict__ Wt) {
  __shared__ float tile[64][65];
  const int bx = blockIdx.x & 15, by = blockIdx.x >> 4;
  const int tx = threadIdx.x & 63, ty = threadIdx.x >> 6;
  const int n0 = bx * 64, k0 = by * 64;
#pragma unroll
  for (int i = 0; i < 16; ++i) {
    int k = ty + i * 4;
    tile[k][tx] = W[(size_t)(k0 + k) * Ec + n0 + tx];
  }
  __syncthreads();
#pragma unroll
  for (int i = 0; i < 16; ++i) {
    int n = ty + i * 4;
    Wt[(size_t)(n0 + n) * Ec + k0 + tx] = (half_t)tile[tx][n];
  }
}

// ---------------- GEMM: C = A(f16 MxK) @ Bt(f16 NxK)^T + bias ----------------
// MODE 0: fp32 out row-major (final Wo GEMM)
// MODE 1: f16 out (B,H,S,D), value*(scale)
// MODE 2: f16 out transposed (B,H,D,S)
// MODE 3: f16 out (B,H,G,D), only rows s<G kept; grid.y = batch, row0=b*S
template <int MODE>
__global__ __launch_bounds__(256) void gemm_k(const half_t* __restrict__ A,
                                              const half_t* __restrict__ Bt,
                                              const float* __restrict__ bias,
                                              void* __restrict__ outp,
                                              float scale) {
  __shared__ __align__(16) half_t Ash[128 * 32];
  __shared__ __align__(16) half_t Bsh[128 * 32];
  const int tid = threadIdx.x;
  const int wv = tid >> 6, lane = tid & 63;
  const int mr = lane & 15, qd = lane >> 4;
  const int wv_m = wv >> 1, wv_n = wv & 1;
  const int col0 = blockIdx.x * 128;
  const int row0 = (MODE == 3) ? blockIdx.y * Sc : blockIdx.y * 128;

  f4 acc[4][4] = {};

  for (int k0 = 0; k0 < Ec; k0 += 32) {
#pragma unroll
    for (int i = 0; i < 2; ++i) {
      int slot = wv * 128 + i * 64 + lane;
      int r = slot >> 2;
      int kc = (slot & 3) ^ (r & 3);  // XOR swizzle for conflict-free frag reads
      gl_lds16(A + (size_t)(row0 + r) * Ec + k0 + kc * 8, Ash + (size_t)(wv * 128 + i * 64) * 8);
      gl_lds16(Bt + (size_t)(col0 + r) * Ec + k0 + kc * 8, Bsh + (size_t)(wv * 128 + i * 64) * 8);
    }
    __syncthreads();
    h8 af[4], bf[4];
#pragma unroll
    for (int mt = 0; mt < 4; ++mt) {
      int r = wv_m * 64 + mt * 16 + mr;
      af[mt] = *(const h8*)(Ash + (size_t)((r << 2) | (qd ^ (r & 3))) * 8);
    }
#pragma unroll
    for (int nt = 0; nt < 4; ++nt) {
      int r = wv_n * 64 + nt * 16 + mr;
      bf[nt] = *(const h8*)(Bsh + (size_t)((r << 2) | (qd ^ (r & 3))) * 8);
    }
#pragma unroll
    for (int mt = 0; mt < 4; ++mt)
#pragma unroll
      for (int nt = 0; nt < 4; ++nt)
        acc[mt][nt] = mfma16(af[mt], bf[nt], acc[mt][nt]);
    __syncthreads();
  }

  // epilogue. C layout: col = lane&15, row = (lane>>4)*4 + reg
#pragma unroll
  for (int mt = 0; mt < 4; ++mt) {
#pragma unroll
    for (int nt = 0; nt < 4; ++nt) {
      const int C = col0 + wv_n * 64 + nt * 16 + mr;
      const float bval = bias[C];
      const int Rbase = row0 + wv_m * 64 + mt * 16 + qd * 4;
      f4 a = acc[mt][nt];
      if (MODE == 0) {
        float* O = (float*)outp;
#pragma unroll
        for (int r = 0; r < 4; ++r)
          O[(size_t)(Rbase + r) * Ec + C] = (a[r] + bval) * scale;
      } else if (MODE == 1) {
        half_t* O = (half_t*)outp;
        const int hh = C >> 6, d = C & 63;
#pragma unroll
        for (int r = 0; r < 4; ++r) {
          int R = Rbase + r;
          int b = R >> 12, s = R & 4095;
          O[((size_t)(b * Hc + hh) * Sc + s) * Dc + d] = (half_t)((a[r] + bval) * scale);
        }
      } else if (MODE == 2) {
        half_t* O = (half_t*)outp;
        const int hh = C >> 6, d = C & 63;
        int b = Rbase >> 12, s = Rbase & 4095;
        h4 pk;
#pragma unroll
        for (int r = 0; r < 4; ++r) pk[r] = (half_t)((a[r] + bval) * scale);
        *(h4*)((half_t*)O + ((size_t)(b * Hc + hh) * Dc + d) * Sc + s) = pk;
      } else {  // MODE 3
        half_t* O = (half_t*)outp;
        const int hh = C >> 6, d = C & 63;
#pragma unroll
        for (int r = 0; r < 4; ++r) {
          int R = Rbase + r;
          int b = R >> 12, s = R & 4095;
          if (s < Gc)
            O[((size_t)(b * Hc + hh) * Gc + s) * Dc + d] = (half_t)((a[r] + bval) * scale);
        }
      }
    }
  }
}

// ---------------- windowed + global-key attention ----------------
// block: 16 queries of one (b,h); slots 0..63 = global keys (kp=slot),
// slots 64..831 = band keys kp = (c-1)*w + slot-64
__global__ __launch_bounds__(256) void win_attn(const half_t* __restrict__ qh,
                                                const half_t* __restrict__ kh,
                                                const half_t* __restrict__ vt,
                                                half_t* __restrict__ ctx) {
  __shared__ __align__(16) float sc[16 * SCP];
  __shared__ float rs[16];
  const int bid = blockIdx.x;
  const int qt = bid & 255, h = (bid >> 8) & 15, b = bid >> 12;
  const int s0 = qt << 4;
  const int c = s0 >> 8;
  const int bs = (c - 1) * Wc;
  const int tid = threadIdx.x, wv = tid >> 6, lane = tid & 63;
  const int mr = lane & 15, qd = lane >> 4;
  const size_t bh = (size_t)(b * Hc + h);
  const half_t* qb = qh + bh * Sc * Dc;
  const half_t* kb = kh + bh * Sc * Dc;

  h8 a0 = *(const h8*)(qb + (size_t)(s0 + mr) * Dc + qd * 8);
  h8 a1 = *(const h8*)(qb + (size_t)(s0 + mr) * Dc + 32 + qd * 8);

  // phase 1: scores -> LDS (waves split the 52 key tiles)
  for (int t = wv; t < 52; t += 4) {
    int slot = t * 16 + mr;
    int kp = (t < 4) ? slot : bs + slot - 64;
    h8 b0 = {}, b1 = {};
    if (kp >= 0 && kp < Sc) {
      b0 = *(const h8*)(kb + (size_t)kp * Dc + qd * 8);
      b1 = *(const h8*)(kb + (size_t)kp * Dc + 32 + qd * 8);
    }
    f4 s = {};
    s = mfma16(a0, b0, s);
    s = mfma16(a1, b1, s);
#pragma unroll
    for (int r = 0; r < 4; ++r) {
      int row = qd * 4 + r;
      int qpos = s0 + row;
      bool valid = (t < 4) || (kp >= Gc && kp < Sc && kp >= qpos - Wc && kp <= qpos + Wc);
      sc[row * SCP + slot] = valid ? s[r] : NEGV;
    }
  }
  __syncthreads();

  // phase 2: row softmax (16 threads per row), p stored back fp32 unnormalized
  {
    const int r = tid >> 4, l = tid & 15;
    float* srow = sc + r * SCP;
    float mx = -1e30f;
    for (int i = l; i < SLOTS; i += 16) mx = fmaxf(mx, srow[i]);
#pragma unroll
    for (int o = 1; o < 16; o <<= 1) mx = fmaxf(mx, __shfl_xor(mx, o));
    float sum = 0.f;
    for (int i = l; i < SLOTS; i += 16) {
      float p = __expf(srow[i] - mx);
      srow[i] = p;
      sum += p;
    }
#pragma unroll
    for (int o = 1; o < 16; o <<= 1) sum += __shfl_xor(sum, o);
    if (l == 0) rs[r] = 1.0f / sum;
  }
  __syncthreads();

  // phase 3: O = P @ V ; wave wv handles dims [wv*16, wv*16+16)
  const int d = wv * 16 + mr;
  const half_t* vb = vt + (bh * Dc + d) * Sc;
  f4 o = {};
  for (int ch = 0; ch < 26; ++ch) {
    int slot0 = ch * 32 + qd * 8;
    const float* pp = sc + mr * SCP + slot0;
    float4 f0 = *(const float4*)pp;
    float4 f1 = *(const float4*)(pp + 4);
    h8 af;
    af[0] = (half_t)f0.x; af[1] = (half_t)f0.y; af[2] = (half_t)f0.z; af[3] = (half_t)f0.w;
    af[4] = (half_t)f1.x; af[5] = (half_t)f1.y; af[6] = (half_t)f1.z; af[7] = (half_t)f1.w;
    int kp0 = (ch < 2) ? slot0 : bs + slot0 - 64;
    h8 bfv = {};
    if (kp0 >= 0 && kp0 <= Sc - 8) bfv = *(const h8*)(vb + kp0);
    o = mfma16(af, bfv, o);
  }
#pragma unroll
  for (int r = 0; r < 4; ++r) {
    int row = qd * 4 + r;
    float val = o[r] * rs[row];
    ctx[(size_t)(b * Sc + s0 + row) * Ec + h * Dc + d] = (half_t)val;
  }
}

// ---------------- global-query attention (3 kernels) ----------------

__global__ __launch_bounds__(256) void gq_scores(const half_t* __restrict__ qgh,
                                                 const half_t* __restrict__ kgh,
                                                 float* __restrict__ Sg) {
  const int st = blockIdx.x & 15, h = (blockIdx.x >> 4) & 15, b = blockIdx.x >> 8;
  const int wv = threadIdx.x >> 6, lane = threadIdx.x & 63;
  const int mr = lane & 15, qd = lane >> 4;
  const size_t bh = (size_t)(b * Hc + h);
  const half_t* qb = qgh + bh * Gc * Dc;
  const half_t* kb = kgh + bh * Sc * Dc;
  float* out = Sg + bh * Gc * Sc;

  h8 a0 = *(const h8*)(qb + (size_t)(wv * 16 + mr) * Dc + qd * 8);
  h8 a1 = *(const h8*)(qb + (size_t)(wv * 16 + mr) * Dc + 32 + qd * 8);
#pragma unroll 4
  for (int nt = 0; nt < 16; ++nt) {
    int s = st * 256 + nt * 16 + mr;
    h8 b0 = *(const h8*)(kb + (size_t)s * Dc + qd * 8);
    h8 b1 = *(const h8*)(kb + (size_t)s * Dc + 32 + qd * 8);
    f4 scv = {};
    scv = mfma16(a0, b0, scv);
    scv = mfma16(a1, b1, scv);
#pragma unroll
    for (int r = 0; r < 4; ++r)
      out[(size_t)(wv * 16 + qd * 4 + r) * Sc + st * 256 + nt * 16 + mr] = scv[r];
  }
}

__global__ __launch_bounds__(256) void gq_softmax(const float* __restrict__ Sg,
                                                  half_t* __restrict__ Pg) {
  const int row = blockIdx.x;
  const float* src = Sg + (size_t)row * Sc;
  half_t* dst = Pg + (size_t)row * Sc;
  const int t = threadIdx.x;
  __shared__ float red[4], reds[4];
  float mx = -1e30f;
  for (int i = t; i < Sc; i += 256) mx = fmaxf(mx, src[i]);
#pragma unroll
  for (int o = 1; o < 64; o <<= 1) mx = fmaxf(mx, __shfl_xor(mx, o));
  if ((t & 63) == 0) red[t >> 6] = mx;
  __syncthreads();
  mx = fmaxf(fmaxf(red[0], red[1]), fmaxf(red[2], red[3]));
  float pv[16];
  float sum = 0.f;
  for (int i = t, j = 0; i < Sc; i += 256, ++j) {
    pv[j] = __expf(src[i] - mx);
    sum += pv[j];
  }
#pragma unroll
  for (int o = 1; o < 64; o <<= 1) sum += __shfl_xor(sum, o);
  if ((t & 63) == 0) reds[t >> 6] = sum;
  __syncthreads();
  sum = reds[0] + reds[1] + reds[2] + reds[3];
  float inv = 1.0f / sum;
  for (int i = t, j = 0; i < Sc; i += 256, ++j) dst[i] = (half_t)(pv[j] * inv);
}

__global__ __launch_bounds__(256) void gq_pv(const half_t* __restrict__ Pg,
                                             const half_t* __restrict__ vgt,
                                             half_t* __restrict__ ctx) {
  const int ds = blockIdx.x & 3, h = (blockIdx.x >> 2) & 15, b = blockIdx.x >> 6;
  const int wv = threadIdx.x >> 6, lane = threadIdx.x & 63;
  const int mr = lane & 15, qd = lane >> 4;
  const size_t bh = (size_t)(b * Hc + h);
  const half_t* pb = Pg + bh * Gc * Sc;
  const int d = ds * 16 + mr;
  const half_t* vb = vgt + (bh * Dc + d) * Sc;
  f4 o = {};
  for (int ch = 0; ch < 128; ++ch) {
    h8 af = *(const h8*)(pb + (size_t)(wv * 16 + mr) * Sc + ch * 32 + qd * 8);
    h8 bf = *(const h8*)(vb + ch * 32 + qd * 8);
    o = mfma16(af, bf, o);
  }
#pragma unroll
  for (int r = 0; r < 4; ++r) {
    int g = wv * 16 + qd * 4 + r;
    ctx[(size_t)(b * Sc + g) * Ec + h * Dc + d] = (half_t)o[r];
  }
}

// ---------------- host launch ----------------

extern "C" void kernel_launch(void* const* d_in, const int* in_sizes, int n_in,
                              void* d_out, int out_size, void* d_ws, size_t ws_size,
                              hipStream_t stream) {
  const float* x   = (const float*)d_in[0];
  const float* Wq  = (const float*)d_in[2];
  const float* bq  = (const float*)d_in[3];
  const float* Wk  = (const float*)d_in[4];
  const float* bk  = (const float*)d_in[5];
  const float* Wv  = (const float*)d_in[6];
  const float* bv  = (const float*)d_in[7];
  const float* Wqg = (const float*)d_in[8];
  const float* bqg = (const float*)d_in[9];
  const float* Wkg = (const float*)d_in[10];
  const float* bkg = (const float*)d_in[11];
  const float* Wvg = (const float*)d_in[12];
  const float* bvg = (const float*)d_in[13];
  const float* Wo  = (const float*)d_in[14];
  const float* bo  = (const float*)d_in[15];
  float* out = (float*)d_out;

  char* ws = (char*)d_ws;
  size_t off = 0;
  auto alloc = [&](size_t bytes) {
    void* p = ws + off;
    off = (off + bytes + 255) & ~(size_t)255;
    return p;
  };
  const size_t BSE2 = (size_t)Bc * Sc * Ec * 2;     // 16.78 MB (f16)
  half_t* xh   = (half_t*)alloc(BSE2);
  half_t* WtQ  = (half_t*)alloc((size_t)Ec * Ec * 2);
  half_t* WtK  = (half_t*)alloc((size_t)Ec * Ec * 2);
  half_t* WtV  = (half_t*)alloc((size_t)Ec * Ec * 2);
  half_t* WtQg = (half_t*)alloc((size_t)Ec * Ec * 2);
  half_t* WtKg = (half_t*)alloc((size_t)Ec * Ec * 2);
  half_t* WtVg = (half_t*)alloc((size_t)Ec * Ec * 2);
  half_t* WtO  = (half_t*)alloc((size_t)Ec * Ec * 2);
  half_t* qh   = (half_t*)alloc(BSE2);              // (B,H,S,D) scaled
  half_t* kh   = (half_t*)alloc(BSE2);              // (B,H,S,D)
  half_t* vt   = (half_t*)alloc(BSE2);              // (B,H,D,S)
  half_t* kgh  = (half_t*)alloc(BSE2);              // (B,H,S,D)
  half_t* vgt  = (half_t*)alloc(BSE2);              // (B,H,D,S)
  half_t* qgh  = (half_t*)alloc((size_t)Bc * Hc * Gc * Dc * 2);  // (B,H,G,D) scaled
  half_t* ctx  = (half_t*)alloc(BSE2);              // (B,S,E)
  float*  Sg   = (float*)alloc((size_t)Bc * Hc * Gc * Sc * 4);
  half_t* Pg   = (half_t*)alloc((size_t)Bc * Hc * Gc * Sc * 2);
  (void)ws_size; (void)in_sizes; (void)n_in; (void)out_size;

  cvt_x_kernel<<<8192, 256, 0, stream>>>(x, xh);
  wcvt_kernel<<<256, 256, 0, stream>>>(Wq, WtQ);
  wcvt_kernel<<<256, 256, 0, stream>>>(Wk, WtK);
  wcvt_kernel<<<256, 256, 0, stream>>>(Wv, WtV);
  wcvt_kernel<<<256, 256, 0, stream>>>(Wqg, WtQg);
  wcvt_kernel<<<256, 256, 0, stream>>>(Wkg, WtKg);
  wcvt_kernel<<<256, 256, 0, stream>>>(Wvg, WtVg);
  wcvt_kernel<<<256, 256, 0, stream>>>(Wo, WtO);

  dim3 gfull(8, 64);
  gemm_k<1><<<gfull, 256, 0, stream>>>(xh, WtQ, bq, qh, QSCALE);
  gemm_k<1><<<gfull, 256, 0, stream>>>(xh, WtK, bk, kh, 1.0f);
  gemm_k<2><<<gfull, 256, 0, stream>>>(xh, WtV, bv, vt, 1.0f);
  gemm_k<1><<<gfull, 256, 0, stream>>>(xh, WtKg, bkg, kgh, 1.0f);
  gemm_k<2><<<gfull, 256, 0, stream>>>(xh, WtVg, bvg, vgt, 1.0f);
  gemm_k<3><<<dim3(8, 2), 256, 0, stream>>>(xh, WtQg, bqg, qgh, QSCALE);

  win_attn<<<Bc * Hc * (Sc / 16), 256, 0, stream>>>(qh, kh, vt, ctx);

  gq_scores<<<Bc * Hc * 16, 256, 0, stream>>>(qgh, kgh, Sg);
  gq_softmax<<<Bc * Hc * Gc, 256, 0, stream>>>(Sg, Pg);
  gq_pv<<<Bc * Hc * 4, 256, 0, stream>>>(Pg, vgt, ctx);

  gemm_k<0><<<gfull, 256, 0, stream>>>(ctx, WtO, bo, out, 1.0f);
}

// Round 2
// 538.075 us; speedup vs baseline: 1.2070x; 1.2070x over previous
//
#include <hip/hip_runtime.h>

typedef _Float16 half_t;
typedef _Float16 h8 __attribute__((ext_vector_type(8)));
typedef _Float16 h4 __attribute__((ext_vector_type(4)));
typedef float f4 __attribute__((ext_vector_type(4)));

#define DEV __device__ __forceinline__

constexpr int Bc = 2, Sc = 4096, Ec = 1024, Hc = 16, Dc = 64, Wc = 256, Gc = 64;
constexpr float QSCALE = 0.125f;     // 1/sqrt(D)
constexpr float NEGV = -1e9f;

DEV f4 mfma16(h8 a, h8 b, f4 c) {
  return __builtin_amdgcn_mfma_f32_16x16x32_f16(a, b, c, 0, 0, 0);
}

DEV void gl_lds16(const half_t* g, half_t* l) {
  __builtin_amdgcn_global_load_lds((const __attribute__((address_space(1))) void*)g,
                                   (__attribute__((address_space(3))) void*)l, 16, 0, 0);
}

// ---------------- conversion kernels ----------------

__global__ void cvt_x_kernel(const float* __restrict__ x, half_t* __restrict__ xh) {
  int i = blockIdx.x * 256 + threadIdx.x;
  float4 v = ((const float4*)x)[i];
  h4 o;
  o[0] = (half_t)v.x; o[1] = (half_t)v.y; o[2] = (half_t)v.z; o[3] = (half_t)v.w;
  ((h4*)xh)[i] = o;
}

// W (K=1024 x N=1024 fp32) -> Wt (N x K f16)
__global__ void wcvt_kernel(const float* __restrict__ W, half_t* __restrict__ Wt) {
  __shared__ float tile[64][65];
  const int bx = blockIdx.x & 15, by = blockIdx.x >> 4;
  const int tx = threadIdx.x & 63, ty = threadIdx.x >> 6;
  const int n0 = bx * 64, k0 = by * 64;
#pragma unroll
  for (int i = 0; i < 16; ++i) {
    int k = ty + i * 4;
    tile[k][tx] = W[(size_t)(k0 + k) * Ec + n0 + tx];
  }
  __syncthreads();
#pragma unroll
  for (int i = 0; i < 16; ++i) {
    int n = ty + i * 4;
    Wt[(size_t)(n0 + n) * Ec + k0 + tx] = (half_t)tile[tx][n];
  }
}

// ---------------- fused projection GEMM: xh(8192x1024) @ Wcat(6144x1024)^T ----------------
// group g = col/1024: 0=q(BHSD,scale) 1=k(BHSD) 2=v(BHDS) 3=kg(BHSD) 4=vg(BHDS) 5=qg(BHGD,scale)
__global__ __launch_bounds__(256) void gemm_proj(const half_t* __restrict__ A,
                                                 const half_t* __restrict__ Bt,
                                                 const float* __restrict__ bcat,
                                                 half_t* __restrict__ qh, half_t* __restrict__ kh,
                                                 half_t* __restrict__ vt, half_t* __restrict__ kgh,
                                                 half_t* __restrict__ vgt, half_t* __restrict__ qgh) {
  __shared__ __align__(16) half_t Ash[128 * 32];
  __shared__ __align__(16) half_t Bsh[128 * 32];
  const int tid = threadIdx.x;
  const int wv = tid >> 6, lane = tid & 63;
  const int mr = lane & 15, qd = lane >> 4;
  const int wv_m = wv >> 1, wv_n = wv & 1;
  const int col0 = blockIdx.x * 128;
  const int row0 = blockIdx.y * 128;
  const int g = col0 >> 10;

  f4 acc[4][4] = {};

  for (int k0 = 0; k0 < Ec; k0 += 32) {
#pragma unroll
    for (int i = 0; i < 2; ++i) {
      int slot = wv * 128 + i * 64 + lane;
      int r = slot >> 2;
      int kc = (slot & 3) ^ (r & 3);
      gl_lds16(A + (size_t)(row0 + r) * Ec + k0 + kc * 8, Ash + (size_t)(wv * 128 + i * 64) * 8);
      gl_lds16(Bt + (size_t)(col0 + r) * Ec + k0 + kc * 8, Bsh + (size_t)(wv * 128 + i * 64) * 8);
    }
    __syncthreads();
    h8 af[4], bf[4];
#pragma unroll
    for (int mt = 0; mt < 4; ++mt) {
      int r = wv_m * 64 + mt * 16 + mr;
      af[mt] = *(const h8*)(Ash + (size_t)((r << 2) | (qd ^ (r & 3))) * 8);
    }
#pragma unroll
    for (int nt = 0; nt < 4; ++nt) {
      int r = wv_n * 64 + nt * 16 + mr;
      bf[nt] = *(const h8*)(Bsh + (size_t)((r << 2) | (qd ^ (r & 3))) * 8);
    }
#pragma unroll
    for (int mt = 0; mt < 4; ++mt)
#pragma unroll
      for (int nt = 0; nt < 4; ++nt)
        acc[mt][nt] = mfma16(af[mt], bf[nt], acc[mt][nt]);
    __syncthreads();
  }

  const float scale = (g == 0 || g == 5) ? QSCALE : 1.0f;
#pragma unroll
  for (int mt = 0; mt < 4; ++mt) {
#pragma unroll
    for (int nt = 0; nt < 4; ++nt) {
      const int C = col0 + wv_n * 64 + nt * 16 + mr;
      const float bval = bcat[C];
      const int c1 = C & 1023, hh = c1 >> 6, d = c1 & 63;
      const int Rbase = row0 + wv_m * 64 + mt * 16 + qd * 4;
      f4 a = acc[mt][nt];
      if (g == 2 || g == 4) {  // transposed (B,H,D,S)
        half_t* O = (g == 2) ? vt : vgt;
        int b = Rbase >> 12, s = Rbase & 4095;
        h4 pk;
#pragma unroll
        for (int r = 0; r < 4; ++r) pk[r] = (half_t)(a[r] + bval);
        *(h4*)(O + ((size_t)(b * Hc + hh) * Dc + d) * Sc + s) = pk;
      } else if (g == 5) {     // qg: (B,H,G,D), rows s<G
#pragma unroll
        for (int r = 0; r < 4; ++r) {
          int R = Rbase + r;
          int b = R >> 12, s = R & 4095;
          if (s < Gc)
            qgh[((size_t)(b * Hc + hh) * Gc + s) * Dc + d] = (half_t)((a[r] + bval) * scale);
        }
      } else {                 // (B,H,S,D)
        half_t* O = (g == 0) ? qh : (g == 1) ? kh : kgh;
#pragma unroll
        for (int r = 0; r < 4; ++r) {
          int R = Rbase + r;
          int b = R >> 12, s = R & 4095;
          O[((size_t)(b * Hc + hh) * Sc + s) * Dc + d] = (half_t)((a[r] + bval) * scale);
        }
      }
    }
  }
}

// ---------------- output GEMM: ctx(8192x1024) @ WtO^T + bo -> fp32 ----------------
__global__ __launch_bounds__(256) void gemm_out(const half_t* __restrict__ A,
                                                const half_t* __restrict__ Bt,
                                                const float* __restrict__ bias,
                                                float* __restrict__ O) {
  __shared__ __align__(16) half_t Ash[128 * 32];
  __shared__ __align__(16) half_t Bsh[128 * 32];
  const int tid = threadIdx.x;
  const int wv = tid >> 6, lane = tid & 63;
  const int mr = lane & 15, qd = lane >> 4;
  const int wv_m = wv >> 1, wv_n = wv & 1;
  const int col0 = blockIdx.x * 128;
  const int row0 = blockIdx.y * 128;

  f4 acc[4][4] = {};

  for (int k0 = 0; k0 < Ec; k0 += 32) {
#pragma unroll
    for (int i = 0; i < 2; ++i) {
      int slot = wv * 128 + i * 64 + lane;
      int r = slot >> 2;
      int kc = (slot & 3) ^ (r & 3);
      gl_lds16(A + (size_t)(row0 + r) * Ec + k0 + kc * 8, Ash + (size_t)(wv * 128 + i * 64) * 8);
      gl_lds16(Bt + (size_t)(col0 + r) * Ec + k0 + kc * 8, Bsh + (size_t)(wv * 128 + i * 64) * 8);
    }
    __syncthreads();
    h8 af[4], bf[4];
#pragma unroll
    for (int mt = 0; mt < 4; ++mt) {
      int r = wv_m * 64 + mt * 16 + mr;
      af[mt] = *(const h8*)(Ash + (size_t)((r << 2) | (qd ^ (r & 3))) * 8);
    }
#pragma unroll
    for (int nt = 0; nt < 4; ++nt) {
      int r = wv_n * 64 + nt * 16 + mr;
      bf[nt] = *(const h8*)(Bsh + (size_t)((r << 2) | (qd ^ (r & 3))) * 8);
    }
#pragma unroll
    for (int mt = 0; mt < 4; ++mt)
#pragma unroll
      for (int nt = 0; nt < 4; ++nt)
        acc[mt][nt] = mfma16(af[mt], bf[nt], acc[mt][nt]);
    __syncthreads();
  }

#pragma unroll
  for (int mt = 0; mt < 4; ++mt) {
#pragma unroll
    for (int nt = 0; nt < 4; ++nt) {
      const int C = col0 + wv_n * 64 + nt * 16 + mr;
      const float bval = bias[C];
      const int Rbase = row0 + wv_m * 64 + mt * 16 + qd * 4;
      f4 a = acc[mt][nt];
#pragma unroll
      for (int r = 0; r < 4; ++r)
        O[(size_t)(Rbase + r) * Ec + C] = a[r] + bval;
    }
  }
}

// ---------------- windowed + global-key attention (flash-style) ----------------
// block: 64 queries of one (b,h). Computes S^T tiles (A=K, B=Q) so each lane
// owns one query's scores; online softmax in registers; O^T accumulated via
// A=V^T, B=P^T. P round-trips through wave-private LDS (no barriers).
__global__ __launch_bounds__(256) void win_attn(const half_t* __restrict__ qh,
                                                const half_t* __restrict__ kh,
                                                const half_t* __restrict__ vt,
                                                half_t* __restrict__ ctx) {
  constexpr int PST = 88;  // P row stride in halves: 16B-aligned rows, 2-way-only banks
  __shared__ __align__(16) half_t Pl[4][16 * PST];
  const int bid = blockIdx.x;
  const int qt = bid & 63, h = (bid >> 6) & 15, b = bid >> 10;
  const int s0 = qt << 6;
  const int tid = threadIdx.x, wv = tid >> 6, lane = tid & 63;
  const int mr = lane & 15, qd = lane >> 4;
  const size_t bh = (size_t)(b * Hc + h);
  const half_t* qb = qh + bh * Sc * Dc;
  const half_t* kb = kh + bh * Sc * Dc;
  const half_t* vb = vt + bh * Dc * Sc;
  half_t* Pw = &Pl[wv][0];

  const int q = s0 + wv * 16 + mr;  // this lane's query (column of S^T)
  const h8 qf0 = *(const h8*)(qb + (size_t)q * Dc + qd * 8);
  const h8 qf1 = *(const h8*)(qb + (size_t)q * Dc + 32 + qd * 8);

  float m_run = -1e30f, l_run = 0.0f;
  f4 acc_o[4] = {};  // O^T: row d = mt*16 + qd*4 + r, col q = mr

  for (int t = 0; t < 10; ++t) {
    const int kp0 = (t == 0) ? 0 : s0 - Wc + (t - 1) * 64;
    if (t > 0 && (kp0 + 63 < Gc || kp0 >= Sc)) continue;  // fully invalid tile
    const bool nomask = (t == 0) ||
                        (kp0 >= s0 + 63 - Wc && kp0 + 63 <= s0 + Wc);

    // ---- S^T tile: 64 slots x 16 queries per wave ----
    f4 sa[4];
#pragma unroll
    for (int mt = 0; mt < 4; ++mt) {
      const int kp = kp0 + mt * 16 + mr;
      h8 kf0 = *(const h8*)(kb + (size_t)kp * Dc + qd * 8);
      h8 kf1 = *(const h8*)(kb + (size_t)kp * Dc + 32 + qd * 8);
      f4 s = {};
      s = mfma16(kf0, qf0, s);
      s = mfma16(kf1, qf1, s);
      sa[mt] = s;
    }
    if (!nomask) {
#pragma unroll
      for (int mt = 0; mt < 4; ++mt)
#pragma unroll
        for (int r = 0; r < 4; ++r) {
          const int kp = kp0 + mt * 16 + qd * 4 + r;
          const bool valid = kp >= Gc && kp >= q - Wc && kp <= q + Wc;
          sa[mt][r] = valid ? sa[mt][r] : NEGV;
        }
    }

    // ---- online softmax (each lane: one query, 16 slot-values) ----
    float tm = -1e30f;
#pragma unroll
    for (int mt = 0; mt < 4; ++mt)
#pragma unroll
      for (int r = 0; r < 4; ++r) tm = fmaxf(tm, sa[mt][r]);
    tm = fmaxf(tm, __shfl_xor(tm, 16));
    tm = fmaxf(tm, __shfl_xor(tm, 32));
    const float mnew = fmaxf(m_run, tm);
    const float alpha = __expf(m_run - mnew);
    m_run = mnew;
    float psum = 0.0f;
#pragma unroll
    for (int mt = 0; mt < 4; ++mt) {
      h4 pk;
#pragma unroll
      for (int r = 0; r < 4; ++r) {
        const float p = __expf(sa[mt][r] - mnew);
        psum += p;
        pk[r] = (half_t)p;
      }
      *(h4*)(Pw + mr * PST + mt * 16 + qd * 4) = pk;  // P[q=mr][s], wave-private
    }
    psum += __shfl_xor(psum, 16);
    psum += __shfl_xor(psum, 32);
    l_run = l_run * alpha + psum;
#pragma unroll
    for (int mt = 0; mt < 4; ++mt)
#pragma unroll
      for (int r = 0; r < 4; ++r) acc_o[mt][r] *= alpha;

    // ---- O^T += V^T @ P^T ----
#pragma unroll
    for (int ks = 0; ks < 2; ++ks) {
      const h8 pf = *(const h8*)(Pw + mr * PST + ks * 32 + qd * 8);
#pragma unroll
      for (int mt = 0; mt < 4; ++mt) {
        const h8 vf = *(const h8*)(vb + (size_t)(mt * 16 + mr) * Sc + kp0 + ks * 32 + qd * 8);
        acc_o[mt] = mfma16(vf, pf, acc_o[mt]);
      }
    }
  }

  const float inv = 1.0f / l_run;
  half_t* crow = ctx + ((size_t)(b * Sc) + q) * Ec + h * Dc;
#pragma unroll
  for (int mt = 0; mt < 4; ++mt) {
    h4 pk;
#pragma unroll
    for (int r = 0; r < 4; ++r) pk[r] = (half_t)(acc_o[mt][r] * inv);
    *(h4*)(crow + mt * 16 + qd * 4) = pk;
  }
}

// ---------------- global-query attention (3 kernels) ----------------

__global__ __launch_bounds__(256) void gq_scores(const half_t* __restrict__ qgh,
                                                 const half_t* __restrict__ kgh,
                                                 float* __restrict__ Sg) {
  const int st = blockIdx.x & 15, h = (blockIdx.x >> 4) & 15, b = blockIdx.x >> 8;
  const int wv = threadIdx.x >> 6, lane = threadIdx.x & 63;
  const int mr = lane & 15, qd = lane >> 4;
  const size_t bh = (size_t)(b * Hc + h);
  const half_t* qb = qgh + bh * Gc * Dc;
  const half_t* kb = kgh + bh * Sc * Dc;
  float* out = Sg + bh * Gc * Sc;

  h8 a0 = *(const h8*)(qb + (size_t)(wv * 16 + mr) * Dc + qd * 8);
  h8 a1 = *(const h8*)(qb + (size_t)(wv * 16 + mr) * Dc + 32 + qd * 8);
#pragma unroll 4
  for (int nt = 0; nt < 16; ++nt) {
    int s = st * 256 + nt * 16 + mr;
    h8 b0 = *(const h8*)(kb + (size_t)s * Dc + qd * 8);
    h8 b1 = *(const h8*)(kb + (size_t)s * Dc + 32 + qd * 8);
    f4 scv = {};
    scv = mfma16(a0, b0, scv);
    scv = mfma16(a1, b1, scv);
#pragma unroll
    for (int r = 0; r < 4; ++r)
      out[(size_t)(wv * 16 + qd * 4 + r) * Sc + st * 256 + nt * 16 + mr] = scv[r];
  }
}

__global__ __launch_bounds__(256) void gq_softmax(const float* __restrict__ Sg,
                                                  half_t* __restrict__ Pg) {
  const int row = blockIdx.x;
  const float* src = Sg + (size_t)row * Sc;
  half_t* dst = Pg + (size_t)row * Sc;
  const int t = threadIdx.x;
  __shared__ float red[4], reds[4];
  float mx = -1e30f;
  for (int i = t; i < Sc; i += 256) mx = fmaxf(mx, src[i]);
#pragma unroll
  for (int o = 1; o < 64; o <<= 1) mx = fmaxf(mx, __shfl_xor(mx, o));
  if ((t & 63) == 0) red[t >> 6] = mx;
  __syncthreads();
  mx = fmaxf(fmaxf(red[0], red[1]), fmaxf(red[2], red[3]));
  float pv[16];
  float sum = 0.f;
  for (int i = t, j = 0; i < Sc; i += 256, ++j) {
    pv[j] = __expf(src[i] - mx);
    sum += pv[j];
  }
#pragma unroll
  for (int o = 1; o < 64; o <<= 1) sum += __shfl_xor(sum, o);
  if ((t & 63) == 0) reds[t >> 6] = sum;
  __syncthreads();
  sum = reds[0] + reds[1] + reds[2] + reds[3];
  float inv = 1.0f / sum;
  for (int i = t, j = 0; i < Sc; i += 256, ++j) dst[i] = (half_t)(pv[j] * inv);
}

__global__ __launch_bounds__(256) void gq_pv(const half_t* __restrict__ Pg,
                                             const half_t* __restrict__ vgt,
                                             half_t* __restrict__ ctx) {
  const int ds = blockIdx.x & 3, h = (blockIdx.x >> 2) & 15, b = blockIdx.x >> 6;
  const int wv = threadIdx.x >> 6, lane = threadIdx.x & 63;
  const int mr = lane & 15, qd = lane >> 4;
  const size_t bh = (size_t)(b * Hc + h);
  const half_t* pb = Pg + bh * Gc * Sc;
  const int d = ds * 16 + mr;
  const half_t* vb = vgt + (bh * Dc + d) * Sc;
  f4 o = {};
  for (int ch = 0; ch < 128; ++ch) {
    h8 af = *(const h8*)(pb + (size_t)(wv * 16 + mr) * Sc + ch * 32 + qd * 8);
    h8 bf = *(const h8*)(vb + ch * 32 + qd * 8);
    o = mfma16(af, bf, o);
  }
#pragma unroll
  for (int r = 0; r < 4; ++r) {
    int g = wv * 16 + qd * 4 + r;
    ctx[(size_t)(b * Sc + g) * Ec + h * Dc + d] = (half_t)o[r];
  }
}

// ---------------- host launch ----------------

extern "C" void kernel_launch(void* const* d_in, const int* in_sizes, int n_in,
                              void* d_out, int out_size, void* d_ws, size_t ws_size,
                              hipStream_t stream) {
  const float* x   = (const float*)d_in[0];
  const float* Wq  = (const float*)d_in[2];
  const float* bq  = (const float*)d_in[3];
  const float* Wk  = (const float*)d_in[4];
  const float* bk  = (const float*)d_in[5];
  const float* Wv  = (const float*)d_in[6];
  const float* bv  = (const float*)d_in[7];
  const float* Wqg = (const float*)d_in[8];
  const float* bqg = (const float*)d_in[9];
  const float* Wkg = (const float*)d_in[10];
  const float* bkg = (const float*)d_in[11];
  const float* Wvg = (const float*)d_in[12];
  const float* bvg = (const float*)d_in[13];
  const float* Wo  = (const float*)d_in[14];
  const float* bo  = (const float*)d_in[15];
  float* out = (float*)d_out;

  char* ws = (char*)d_ws;
  size_t off = 0;
  auto alloc = [&](size_t bytes) {
    void* p = ws + off;
    off = (off + bytes + 255) & ~(size_t)255;
    return p;
  };
  const size_t BSE2 = (size_t)Bc * Sc * Ec * 2;
  const size_t W2 = (size_t)Ec * Ec * 2;
  half_t* xh   = (half_t*)alloc(BSE2);
  half_t* Wcat = (half_t*)alloc(W2 * 6);            // 6 transposed f16 weights
  half_t* WtO  = (half_t*)alloc(W2);
  float*  bcat = (float*)alloc(6 * Ec * 4);
  half_t* qh   = (half_t*)alloc(BSE2);              // (B,H,S,D) scaled
  half_t* kh   = (half_t*)alloc(BSE2);              // (B,H,S,D)
  half_t* vt   = (half_t*)alloc(BSE2);              // (B,H,D,S)
  half_t* kgh  = (half_t*)alloc(BSE2);              // (B,H,S,D)
  half_t* vgt  = (half_t*)alloc(BSE2);              // (B,H,D,S)
  half_t* qgh  = (half_t*)alloc((size_t)Bc * Hc * Gc * Dc * 2);
  half_t* ctx  = (half_t*)alloc(BSE2);
  float*  Sg   = (float*)alloc((size_t)Bc * Hc * Gc * Sc * 4);
  half_t* Pg   = (half_t*)alloc((size_t)Bc * Hc * Gc * Sc * 2);
  (void)ws_size; (void)in_sizes; (void)n_in; (void)out_size;

  cvt_x_kernel<<<8192, 256, 0, stream>>>(x, xh);
  wcvt_kernel<<<256, 256, 0, stream>>>(Wq,  Wcat + 0 * Ec * Ec);
  wcvt_kernel<<<256, 256, 0, stream>>>(Wk,  Wcat + 1 * (size_t)Ec * Ec);
  wcvt_kernel<<<256, 256, 0, stream>>>(Wv,  Wcat + 2 * (size_t)Ec * Ec);
  wcvt_kernel<<<256, 256, 0, stream>>>(Wkg, Wcat + 3 * (size_t)Ec * Ec);
  wcvt_kernel<<<256, 256, 0, stream>>>(Wvg, Wcat + 4 * (size_t)Ec * Ec);
  wcvt_kernel<<<256, 256, 0, stream>>>(Wqg, Wcat + 5 * (size_t)Ec * Ec);
  wcvt_kernel<<<256, 256, 0, stream>>>(Wo,  WtO);
  hipMemcpyAsync(bcat + 0 * Ec, bq,  Ec * 4, hipMemcpyDeviceToDevice, stream);
  hipMemcpyAsync(bcat + 1 * Ec, bk,  Ec * 4, hipMemcpyDeviceToDevice, stream);
  hipMemcpyAsync(bcat + 2 * Ec, bv,  Ec * 4, hipMemcpyDeviceToDevice, stream);
  hipMemcpyAsync(bcat + 3 * Ec, bkg, Ec * 4, hipMemcpyDeviceToDevice, stream);
  hipMemcpyAsync(bcat + 4 * Ec, bvg, Ec * 4, hipMemcpyDeviceToDevice, stream);
  hipMemcpyAsync(bcat + 5 * Ec, bqg, Ec * 4, hipMemcpyDeviceToDevice, stream);

  gemm_proj<<<dim3(48, 64), 256, 0, stream>>>(xh, Wcat, bcat, qh, kh, vt, kgh, vgt, qgh);

  win_attn<<<Bc * Hc * (Sc / 64), 256, 0, stream>>>(qh, kh, vt, ctx);

  gq_scores<<<Bc * Hc * 16, 256, 0, stream>>>(qgh, kgh, Sg);
  gq_softmax<<<Bc * Hc * Gc, 256, 0, stream>>>(Sg, Pg);
  gq_pv<<<Bc * Hc * 4, 256, 0, stream>>>(Pg, vgt, ctx);

  gemm_out<<<dim3(8, 64), 256, 0, stream>>>(ctx, WtO, bo, out);
}

// Round 3
// 486.146 us; speedup vs baseline: 1.3359x; 1.1068x over previous
//
#include <hip/hip_runtime.h>

typedef _Float16 half_t;
typedef _Float16 h8 __attribute__((ext_vector_type(8)));
typedef _Float16 h4 __attribute__((ext_vector_type(4)));
typedef float f4 __attribute__((ext_vector_type(4)));

#define DEV __device__ __forceinline__

constexpr int Bc = 2, Sc = 4096, Ec = 1024, Hc = 16, Dc = 64, Wc = 256, Gc = 64;
constexpr float QSCALE = 0.125f;     // 1/sqrt(D)
constexpr float NEGV = -1e9f;

DEV f4 mfma16(h8 a, h8 b, f4 c) {
  return __builtin_amdgcn_mfma_f32_16x16x32_f16(a, b, c, 0, 0, 0);
}

DEV void gl_lds16(const half_t* g, half_t* l) {
  __builtin_amdgcn_global_load_lds((const __attribute__((address_space(1))) void*)g,
                                   (__attribute__((address_space(3))) void*)l, 16, 0, 0);
}

// ---------------- conversion kernels ----------------

__global__ void cvt_x_kernel(const float* __restrict__ x, half_t* __restrict__ xh) {
  int i = blockIdx.x * 256 + threadIdx.x;
  float4 v = ((const float4*)x)[i];
  h4 o;
  o[0] = (half_t)v.x; o[1] = (half_t)v.y; o[2] = (half_t)v.z; o[3] = (half_t)v.w;
  ((h4*)xh)[i] = o;
}

// W (K=1024 x N=1024 fp32) -> Wt (N x K f16)
__global__ void wcvt_kernel(const float* __restrict__ W, half_t* __restrict__ Wt) {
  __shared__ float tile[64][65];
  const int bx = blockIdx.x & 15, by = blockIdx.x >> 4;
  const int tx = threadIdx.x & 63, ty = threadIdx.x >> 6;
  const int n0 = bx * 64, k0 = by * 64;
#pragma unroll
  for (int i = 0; i < 16; ++i) {
    int k = ty + i * 4;
    tile[k][tx] = W[(size_t)(k0 + k) * Ec + n0 + tx];
  }
  __syncthreads();
#pragma unroll
  for (int i = 0; i < 16; ++i) {
    int n = ty + i * 4;
    Wt[(size_t)(n0 + n) * Ec + k0 + tx] = (half_t)tile[tx][n];
  }
}

// ---------------- fused projection GEMM: xh(8192x1024) @ Wcat(6144x1024)^T ----------------
// group g = col/1024: 0=q(BHSD,scale) 1=k(BHSD) 2=v(BHDS) 3=kg(BHSD) 4=vg(BHDS) 5=qg(BHGD,scale)
__global__ __launch_bounds__(256) void gemm_proj(const half_t* __restrict__ A,
                                                 const half_t* __restrict__ Bt,
                                                 const float* __restrict__ bcat,
                                                 half_t* __restrict__ qh, half_t* __restrict__ kh,
                                                 half_t* __restrict__ vt, half_t* __restrict__ kgh,
                                                 half_t* __restrict__ vgt, half_t* __restrict__ qgh) {
  __shared__ __align__(16) half_t Ash[128 * 32];
  __shared__ __align__(16) half_t Bsh[128 * 32];
  const int tid = threadIdx.x;
  const int wv = tid >> 6, lane = tid & 63;
  const int mr = lane & 15, qd = lane >> 4;
  const int wv_m = wv >> 1, wv_n = wv & 1;
  const int col0 = blockIdx.x * 128;
  const int row0 = blockIdx.y * 128;
  const int g = col0 >> 10;

  f4 acc[4][4] = {};

  for (int k0 = 0; k0 < Ec; k0 += 32) {
#pragma unroll
    for (int i = 0; i < 2; ++i) {
      int slot = wv * 128 + i * 64 + lane;
      int r = slot >> 2;
      int kc = (slot & 3) ^ (r & 3);
      gl_lds16(A + (size_t)(row0 + r) * Ec + k0 + kc * 8, Ash + (size_t)(wv * 128 + i * 64) * 8);
      gl_lds16(Bt + (size_t)(col0 + r) * Ec + k0 + kc * 8, Bsh + (size_t)(wv * 128 + i * 64) * 8);
    }
    __syncthreads();
    h8 af[4], bf[4];
#pragma unroll
    for (int mt = 0; mt < 4; ++mt) {
      int r = wv_m * 64 + mt * 16 + mr;
      af[mt] = *(const h8*)(Ash + (size_t)((r << 2) | (qd ^ (r & 3))) * 8);
    }
#pragma unroll
    for (int nt = 0; nt < 4; ++nt) {
      int r = wv_n * 64 + nt * 16 + mr;
      bf[nt] = *(const h8*)(Bsh + (size_t)((r << 2) | (qd ^ (r & 3))) * 8);
    }
#pragma unroll
    for (int mt = 0; mt < 4; ++mt)
#pragma unroll
      for (int nt = 0; nt < 4; ++nt)
        acc[mt][nt] = mfma16(af[mt], bf[nt], acc[mt][nt]);
    __syncthreads();
  }

  const float scale = (g == 0 || g == 5) ? QSCALE : 1.0f;
#pragma unroll
  for (int mt = 0; mt < 4; ++mt) {
#pragma unroll
    for (int nt = 0; nt < 4; ++nt) {
      const int C = col0 + wv_n * 64 + nt * 16 + mr;
      const float bval = bcat[C];
      const int c1 = C & 1023, hh = c1 >> 6, d = c1 & 63;
      const int Rbase = row0 + wv_m * 64 + mt * 16 + qd * 4;
      f4 a = acc[mt][nt];
      if (g == 2 || g == 4) {  // transposed (B,H,D,S)
        half_t* O = (g == 2) ? vt : vgt;
        int b = Rbase >> 12, s = Rbase & 4095;
        h4 pk;
#pragma unroll
        for (int r = 0; r < 4; ++r) pk[r] = (half_t)(a[r] + bval);
        *(h4*)(O + ((size_t)(b * Hc + hh) * Dc + d) * Sc + s) = pk;
      } else if (g == 5) {     // qg: (B,H,G,D), rows s<G
#pragma unroll
        for (int r = 0; r < 4; ++r) {
          int R = Rbase + r;
          int b = R >> 12, s = R & 4095;
          if (s < Gc)
            qgh[((size_t)(b * Hc + hh) * Gc + s) * Dc + d] = (half_t)((a[r] + bval) * scale);
        }
      } else {                 // (B,H,S,D)
        half_t* O = (g == 0) ? qh : (g == 1) ? kh : kgh;
#pragma unroll
        for (int r = 0; r < 4; ++r) {
          int R = Rbase + r;
          int b = R >> 12, s = R & 4095;
          O[((size_t)(b * Hc + hh) * Sc + s) * Dc + d] = (half_t)((a[r] + bval) * scale);
        }
      }
    }
  }
}

// ---------------- output GEMM: ctx(8192x1024) @ WtO^T + bo -> fp32 ----------------
__global__ __launch_bounds__(256) void gemm_out(const half_t* __restrict__ A,
                                                const half_t* __restrict__ Bt,
                                                const float* __restrict__ bias,
                                                float* __restrict__ O) {
  __shared__ __align__(16) half_t Ash[128 * 32];
  __shared__ __align__(16) half_t Bsh[128 * 32];
  const int tid = threadIdx.x;
  const int wv = tid >> 6, lane = tid & 63;
  const int mr = lane & 15, qd = lane >> 4;
  const int wv_m = wv >> 1, wv_n = wv & 1;
  const int col0 = blockIdx.x * 128;
  const int row0 = blockIdx.y * 128;

  f4 acc[4][4] = {};

  for (int k0 = 0; k0 < Ec; k0 += 32) {
#pragma unroll
    for (int i = 0; i < 2; ++i) {
      int slot = wv * 128 + i * 64 + lane;
      int r = slot >> 2;
      int kc = (slot & 3) ^ (r & 3);
      gl_lds16(A + (size_t)(row0 + r) * Ec + k0 + kc * 8, Ash + (size_t)(wv * 128 + i * 64) * 8);
      gl_lds16(Bt + (size_t)(col0 + r) * Ec + k0 + kc * 8, Bsh + (size_t)(wv * 128 + i * 64) * 8);
    }
    __syncthreads();
    h8 af[4], bf[4];
#pragma unroll
    for (int mt = 0; mt < 4; ++mt) {
      int r = wv_m * 64 + mt * 16 + mr;
      af[mt] = *(const h8*)(Ash + (size_t)((r << 2) | (qd ^ (r & 3))) * 8);
    }
#pragma unroll
    for (int nt = 0; nt < 4; ++nt) {
      int r = wv_n * 64 + nt * 16 + mr;
      bf[nt] = *(const h8*)(Bsh + (size_t)((r << 2) | (qd ^ (r & 3))) * 8);
    }
#pragma unroll
    for (int mt = 0; mt < 4; ++mt)
#pragma unroll
      for (int nt = 0; nt < 4; ++nt)
        acc[mt][nt] = mfma16(af[mt], bf[nt], acc[mt][nt]);
    __syncthreads();
  }

#pragma unroll
  for (int mt = 0; mt < 4; ++mt) {
#pragma unroll
    for (int nt = 0; nt < 4; ++nt) {
      const int C = col0 + wv_n * 64 + nt * 16 + mr;
      const float bval = bias[C];
      const int Rbase = row0 + wv_m * 64 + mt * 16 + qd * 4;
      f4 a = acc[mt][nt];
#pragma unroll
      for (int r = 0; r < 4; ++r)
        O[(size_t)(Rbase + r) * Ec + C] = a[r] + bval;
    }
  }
}

// ---------------- windowed + global-key attention (flash-style, LDS-staged) ----------------
// block: 256 queries (one window chunk) of one (b,h); 4 waves x 64 queries.
// K/V tiles (64 keys) staged to LDS via async global_load_lds, double-buffered,
// shared by all waves. Source-side XOR swizzle -> uniform bank groups for
// ds_read_b128 fragment reads. Online softmax per lane (1 query / lane / q-tile).
__global__ __launch_bounds__(256) void win_attn(const half_t* __restrict__ qh,
                                                const half_t* __restrict__ kh,
                                                const half_t* __restrict__ vt,
                                                half_t* __restrict__ ctx) {
  constexpr int PST = 88;  // P row stride (halves): 16B aligned, 2-way-only banks
  __shared__ __align__(16) half_t Kb[2][64 * 64];
  __shared__ __align__(16) half_t Vb[2][64 * 64];
  __shared__ __align__(16) half_t Pl[4][16 * PST];
  const int bid = blockIdx.x;
  const int qc = bid & 15, h = (bid >> 4) & 15, b = bid >> 8;
  const int qs = qc << 8;
  const int tid = threadIdx.x, wv = tid >> 6, lane = tid & 63;
  const int mr = lane & 15, qd = lane >> 4;
  const int qw = qs + wv * 64;  // this wave's 64 queries
  const size_t bh = (size_t)(b * Hc + h);
  const half_t* qb = qh + bh * Sc * Dc;
  const half_t* kb = kh + bh * Sc * Dc;
  const half_t* vb = vt + bh * Dc * Sc;
  half_t* Pw = &Pl[wv][0];

  // Q fragments (held in registers): qf[qt][dh]
  h8 qf[4][2];
#pragma unroll
  for (int qt = 0; qt < 4; ++qt) {
    const half_t* qrow = qb + (size_t)(qw + qt * 16 + mr) * Dc;
    qf[qt][0] = *(const h8*)(qrow + qd * 8);
    qf[qt][1] = *(const h8*)(qrow + 32 + qd * 8);
  }

  // tile list: tiles[0]=global keys (kp0=0, unmasked); rest = band tiles
  int tiles[14];
  int nT = 0;
  tiles[nT++] = 0;
  {
    int lo = qs - Wc; if (lo < Gc) lo = Gc;
    int hi = qs + 448; if (hi > Sc - 64) hi = Sc - 64;
    for (int kp0 = lo; kp0 <= hi; kp0 += 64) tiles[nT++] = kp0;
  }

  auto stage = [&](int kp0, int bi) {
#pragma unroll
    for (int i = 0; i < 2; ++i) {
      const int seg = wv * 2 + i;
      const int s = seg * 64 + lane;
      const int r = s >> 3;
      const int kc = (s & 7) ^ (r & 7);  // source-side swizzle
      gl_lds16(kb + (size_t)(kp0 + r) * Dc + kc * 8, &Kb[bi][seg * 512]);
      gl_lds16(vb + (size_t)r * Sc + kp0 + kc * 8, &Vb[bi][seg * 512]);
    }
  };

  float m_run[4], l_run[4];
  f4 acc[4][4] = {};
#pragma unroll
  for (int qt = 0; qt < 4; ++qt) { m_run[qt] = -1e30f; l_run[qt] = 0.f; }

  stage(tiles[0], 0);

  for (int t = 0; t < nT; ++t) {
    __syncthreads();  // staged tile t visible; prev compute done
    if (t + 1 < nT) stage(tiles[t + 1], (t + 1) & 1);
    const int kp0 = tiles[t];
    // wave-level skip of fully-masked band tiles (band only; global always live)
    if (t > 0 && (kp0 > qw + 319 || kp0 + 63 < qw - Wc)) continue;

    const half_t* BK = Kb[t & 1];
    const half_t* BV = Vb[t & 1];
    h8 kf[4][2], vf[4][2];
#pragma unroll
    for (int mt = 0; mt < 4; ++mt) {
      const int row = mt * 16 + mr, r7 = row & 7;
      kf[mt][0] = *(const h8*)(BK + (size_t)(row * 8 + (qd ^ r7)) * 8);
      kf[mt][1] = *(const h8*)(BK + (size_t)(row * 8 + ((qd + 4) ^ r7)) * 8);
      vf[mt][0] = *(const h8*)(BV + (size_t)(row * 8 + (qd ^ r7)) * 8);
      vf[mt][1] = *(const h8*)(BV + (size_t)(row * 8 + ((qd + 4) ^ r7)) * 8);
    }
    const bool nomask = (t == 0) || (kp0 >= qw - 193 && kp0 <= qw + 193);

#pragma unroll
    for (int qt = 0; qt < 4; ++qt) {
      // S^T tile: rows=64 slots, cols = this wave's 16 queries (q-tile qt)
      f4 sa[4];
#pragma unroll
      for (int mt = 0; mt < 4; ++mt) {
        f4 s = {};
        s = mfma16(kf[mt][0], qf[qt][0], s);
        s = mfma16(kf[mt][1], qf[qt][1], s);
        sa[mt] = s;
      }
      const int q = qw + qt * 16 + mr;
      if (!nomask) {
#pragma unroll
        for (int mt = 0; mt < 4; ++mt)
#pragma unroll
          for (int r = 0; r < 4; ++r) {
            const int kp = kp0 + mt * 16 + qd * 4 + r;
            if (kp < q - Wc || kp > q + Wc) sa[mt][r] = NEGV;
          }
      }
      // online softmax: lane owns query q; its 16 slot-values + partner lanes
      float tm = -1e30f;
#pragma unroll
      for (int mt = 0; mt < 4; ++mt)
#pragma unroll
        for (int r = 0; r < 4; ++r) tm = fmaxf(tm, sa[mt][r]);
      tm = fmaxf(tm, __shfl_xor(tm, 16));
      tm = fmaxf(tm, __shfl_xor(tm, 32));
      const float mnew = fmaxf(m_run[qt], tm);
      const float alpha = __expf(m_run[qt] - mnew);
      m_run[qt] = mnew;
      float psum = 0.0f;
#pragma unroll
      for (int mt = 0; mt < 4; ++mt) {
        h4 pk;
#pragma unroll
        for (int r = 0; r < 4; ++r) {
          const float p = __expf(sa[mt][r] - mnew);
          psum += p;
          pk[r] = (half_t)p;
        }
        *(h4*)(Pw + mr * PST + mt * 16 + qd * 4) = pk;  // P[q=mr][slot]
      }
      psum += __shfl_xor(psum, 16);
      psum += __shfl_xor(psum, 32);
      l_run[qt] = l_run[qt] * alpha + psum;
#pragma unroll
      for (int mt = 0; mt < 4; ++mt)
#pragma unroll
        for (int r = 0; r < 4; ++r) acc[qt][mt][r] *= alpha;
      // PV: O^T += V^T @ P^T  (B-frag: P[q=mr][qd*8..], via wave-private LDS)
      const h8 p0 = *(const h8*)(Pw + mr * PST + qd * 8);
      const h8 p1 = *(const h8*)(Pw + mr * PST + 32 + qd * 8);
#pragma unroll
      for (int mt = 0; mt < 4; ++mt) {
        acc[qt][mt] = mfma16(vf[mt][0], p0, acc[qt][mt]);
        acc[qt][mt] = mfma16(vf[mt][1], p1, acc[qt][mt]);
      }
    }
  }

#pragma unroll
  for (int qt = 0; qt < 4; ++qt) {
    const float inv = 1.0f / l_run[qt];
    const int q = qw + qt * 16 + mr;
    half_t* crow = ctx + ((size_t)(b * Sc) + q) * Ec + h * Dc;
#pragma unroll
    for (int mt = 0; mt < 4; ++mt) {
      h4 pk;
#pragma unroll
      for (int r = 0; r < 4; ++r) pk[r] = (half_t)(acc[qt][mt][r] * inv);
      *(h4*)(crow + mt * 16 + qd * 4) = pk;
    }
  }
}

// ---------------- global-query attention (3 kernels) ----------------

__global__ __launch_bounds__(256) void gq_scores(const half_t* __restrict__ qgh,
                                                 const half_t* __restrict__ kgh,
                                                 float* __restrict__ Sg) {
  const int st = blockIdx.x & 15, h = (blockIdx.x >> 4) & 15, b = blockIdx.x >> 8;
  const int wv = threadIdx.x >> 6, lane = threadIdx.x & 63;
  const int mr = lane & 15, qd = lane >> 4;
  const size_t bh = (size_t)(b * Hc + h);
  const half_t* qb = qgh + bh * Gc * Dc;
  const half_t* kb = kgh + bh * Sc * Dc;
  float* out = Sg + bh * Gc * Sc;

  h8 a0 = *(const h8*)(qb + (size_t)(wv * 16 + mr) * Dc + qd * 8);
  h8 a1 = *(const h8*)(qb + (size_t)(wv * 16 + mr) * Dc + 32 + qd * 8);
#pragma unroll 4
  for (int nt = 0; nt < 16; ++nt) {
    int s = st * 256 + nt * 16 + mr;
    h8 b0 = *(const h8*)(kb + (size_t)s * Dc + qd * 8);
    h8 b1 = *(const h8*)(kb + (size_t)s * Dc + 32 + qd * 8);
    f4 scv = {};
    scv = mfma16(a0, b0, scv);
    scv = mfma16(a1, b1, scv);
#pragma unroll
    for (int r = 0; r < 4; ++r)
      out[(size_t)(wv * 16 + qd * 4 + r) * Sc + st * 256 + nt * 16 + mr] = scv[r];
  }
}

__global__ __launch_bounds__(256) void gq_softmax(const float* __restrict__ Sg,
                                                  half_t* __restrict__ Pg) {
  const int row = blockIdx.x;
  const float* src = Sg + (size_t)row * Sc;
  half_t* dst = Pg + (size_t)row * Sc;
  const int t = threadIdx.x;
  __shared__ float red[4], reds[4];
  float mx = -1e30f;
  for (int i = t; i < Sc; i += 256) mx = fmaxf(mx, src[i]);
#pragma unroll
  for (int o = 1; o < 64; o <<= 1) mx = fmaxf(mx, __shfl_xor(mx, o));
  if ((t & 63) == 0) red[t >> 6] = mx;
  __syncthreads();
  mx = fmaxf(fmaxf(red[0], red[1]), fmaxf(red[2], red[3]));
  float pv[16];
  float sum = 0.f;
  for (int i = t, j = 0; i < Sc; i += 256, ++j) {
    pv[j] = __expf(src[i] - mx);
    sum += pv[j];
  }
#pragma unroll
  for (int o = 1; o < 64; o <<= 1) sum += __shfl_xor(sum, o);
  if ((t & 63) == 0) reds[t >> 6] = sum;
  __syncthreads();
  sum = reds[0] + reds[1] + reds[2] + reds[3];
  float inv = 1.0f / sum;
  for (int i = t, j = 0; i < Sc; i += 256, ++j) dst[i] = (half_t)(pv[j] * inv);
}

__global__ __launch_bounds__(256) void gq_pv(const half_t* __restrict__ Pg,
                                             const half_t* __restrict__ vgt,
                                             half_t* __restrict__ ctx) {
  const int ds = blockIdx.x & 3, h = (blockIdx.x >> 2) & 15, b = blockIdx.x >> 6;
  const int wv = threadIdx.x >> 6, lane = threadIdx.x & 63;
  const int mr = lane & 15, qd = lane >> 4;
  const size_t bh = (size_t)(b * Hc + h);
  const half_t* pb = Pg + bh * Gc * Sc;
  const int d = ds * 16 + mr;
  const half_t* vb = vgt + (bh * Dc + d) * Sc;
  f4 o = {};
  for (int ch = 0; ch < 128; ++ch) {
    h8 af = *(const h8*)(pb + (size_t)(wv * 16 + mr) * Sc + ch * 32 + qd * 8);
    h8 bf = *(const h8*)(vb + ch * 32 + qd * 8);
    o = mfma16(af, bf, o);
  }
#pragma unroll
  for (int r = 0; r < 4; ++r) {
    int g = wv * 16 + qd * 4 + r;
    ctx[(size_t)(b * Sc + g) * Ec + h * Dc + d] = (half_t)o[r];
  }
}

// ---------------- host launch ----------------

extern "C" void kernel_launch(void* const* d_in, const int* in_sizes, int n_in,
                              void* d_out, int out_size, void* d_ws, size_t ws_size,
                              hipStream_t stream) {
  const float* x   = (const float*)d_in[0];
  const float* Wq  = (const float*)d_in[2];
  const float* bq  = (const float*)d_in[3];
  const float* Wk  = (const float*)d_in[4];
  const float* bk  = (const float*)d_in[5];
  const float* Wv  = (const float*)d_in[6];
  const float* bv  = (const float*)d_in[7];
  const float* Wqg = (const float*)d_in[8];
  const float* bqg = (const float*)d_in[9];
  const float* Wkg = (const float*)d_in[10];
  const float* bkg = (const float*)d_in[11];
  const float* Wvg = (const float*)d_in[12];
  const float* bvg = (const float*)d_in[13];
  const float* Wo  = (const float*)d_in[14];
  const float* bo  = (const float*)d_in[15];
  float* out = (float*)d_out;

  char* ws = (char*)d_ws;
  size_t off = 0;
  auto alloc = [&](size_t bytes) {
    void* p = ws + off;
    off = (off + bytes + 255) & ~(size_t)255;
    return p;
  };
  const size_t BSE2 = (size_t)Bc * Sc * Ec * 2;
  const size_t W2 = (size_t)Ec * Ec * 2;
  half_t* xh   = (half_t*)alloc(BSE2);
  half_t* Wcat = (half_t*)alloc(W2 * 6);            // 6 transposed f16 weights
  half_t* WtO  = (half_t*)alloc(W2);
  float*  bcat = (float*)alloc(6 * Ec * 4);
  half_t* qh   = (half_t*)alloc(BSE2);              // (B,H,S,D) scaled
  half_t* kh   = (half_t*)alloc(BSE2);              // (B,H,S,D)
  half_t* vt   = (half_t*)alloc(BSE2);              // (B,H,D,S)
  half_t* kgh  = (half_t*)alloc(BSE2);              // (B,H,S,D)
  half_t* vgt  = (half_t*)alloc(BSE2);              // (B,H,D,S)
  half_t* qgh  = (half_t*)alloc((size_t)Bc * Hc * Gc * Dc * 2);
  half_t* ctx  = (half_t*)alloc(BSE2);
  float*  Sg   = (float*)alloc((size_t)Bc * Hc * Gc * Sc * 4);
  half_t* Pg   = (half_t*)alloc((size_t)Bc * Hc * Gc * Sc * 2);
  (void)ws_size; (void)in_sizes; (void)n_in; (void)out_size;

  cvt_x_kernel<<<8192, 256, 0, stream>>>(x, xh);
  wcvt_kernel<<<256, 256, 0, stream>>>(Wq,  Wcat + 0 * Ec * Ec);
  wcvt_kernel<<<256, 256, 0, stream>>>(Wk,  Wcat + 1 * (size_t)Ec * Ec);
  wcvt_kernel<<<256, 256, 0, stream>>>(Wv,  Wcat + 2 * (size_t)Ec * Ec);
  wcvt_kernel<<<256, 256, 0, stream>>>(Wkg, Wcat + 3 * (size_t)Ec * Ec);
  wcvt_kernel<<<256, 256, 0, stream>>>(Wvg, Wcat + 4 * (size_t)Ec * Ec);
  wcvt_kernel<<<256, 256, 0, stream>>>(Wqg, Wcat + 5 * (size_t)Ec * Ec);
  wcvt_kernel<<<256, 256, 0, stream>>>(Wo,  WtO);
  hipMemcpyAsync(bcat + 0 * Ec, bq,  Ec * 4, hipMemcpyDeviceToDevice, stream);
  hipMemcpyAsync(bcat + 1 * Ec, bk,  Ec * 4, hipMemcpyDeviceToDevice, stream);
  hipMemcpyAsync(bcat + 2 * Ec, bv,  Ec * 4, hipMemcpyDeviceToDevice, stream);
  hipMemcpyAsync(bcat + 3 * Ec, bkg, Ec * 4, hipMemcpyDeviceToDevice, stream);
  hipMemcpyAsync(bcat + 4 * Ec, bvg, Ec * 4, hipMemcpyDeviceToDevice, stream);
  hipMemcpyAsync(bcat + 5 * Ec, bqg, Ec * 4, hipMemcpyDeviceToDevice, stream);

  gemm_proj<<<dim3(48, 64), 256, 0, stream>>>(xh, Wcat, bcat, qh, kh, vt, kgh, vgt, qgh);

  win_attn<<<Bc * Hc * (Sc / 256), 256, 0, stream>>>(qh, kh, vt, ctx);

  gq_scores<<<Bc * Hc * 16, 256, 0, stream>>>(qgh, kgh, Sg);
  gq_softmax<<<Bc * Hc * Gc, 256, 0, stream>>>(Sg, Pg);
  gq_pv<<<Bc * Hc * 4, 256, 0, stream>>>(Pg, vgt, ctx);

  gemm_out<<<dim3(8, 64), 256, 0, stream>>>(ctx, WtO, bo, out);
}

// Round 4
// 458.717 us; speedup vs baseline: 1.4158x; 1.0598x over previous
//
#include <hip/hip_runtime.h>

typedef _Float16 half_t;
typedef _Float16 h8 __attribute__((ext_vector_type(8)));
typedef _Float16 h4 __attribute__((ext_vector_type(4)));
typedef float f4 __attribute__((ext_vector_type(4)));

#define DEV __device__ __forceinline__

constexpr int Bc = 2, Sc = 4096, Ec = 1024, Hc = 16, Dc = 64, Wc = 256, Gc = 64;
constexpr float QSCALE = 0.125f;     // 1/sqrt(D)
constexpr float NEGV = -1e9f;

DEV f4 mfma16(h8 a, h8 b, f4 c) {
  return __builtin_amdgcn_mfma_f32_16x16x32_f16(a, b, c, 0, 0, 0);
}

DEV void gl_lds16(const half_t* g, half_t* l) {
  __builtin_amdgcn_global_load_lds((const __attribute__((address_space(1))) void*)g,
                                   (__attribute__((address_space(3))) void*)l, 16, 0, 0);
}

// ---------------- conversion kernels ----------------

__global__ void cvt_x_kernel(const float* __restrict__ x, half_t* __restrict__ xh) {
  int i = blockIdx.x * 256 + threadIdx.x;
  float4 v = ((const float4*)x)[i];
  h4 o;
  o[0] = (half_t)v.x; o[1] = (half_t)v.y; o[2] = (half_t)v.z; o[3] = (half_t)v.w;
  ((h4*)xh)[i] = o;
}

// all 7 weights (K x N fp32) -> (N x K f16), one dispatch; blockIdx.y selects
__global__ void wcvt_all(const float* __restrict__ Wq, const float* __restrict__ Wk,
                         const float* __restrict__ Wv, const float* __restrict__ Wkg,
                         const float* __restrict__ Wvg, const float* __restrict__ Wqg,
                         const float* __restrict__ Wo,
                         half_t* __restrict__ Wcat, half_t* __restrict__ WtQg,
                         half_t* __restrict__ WtO) {
  __shared__ float tile[64][65];
  const int y = blockIdx.y;
  const float* W = (y == 0) ? Wq : (y == 1) ? Wk : (y == 2) ? Wv :
                   (y == 3) ? Wkg : (y == 4) ? Wvg : (y == 5) ? Wqg : Wo;
  half_t* Wt = (y < 5) ? (Wcat + (size_t)y * Ec * Ec) : (y == 5) ? WtQg : WtO;
  const int bx = blockIdx.x & 15, by = blockIdx.x >> 4;
  const int tx = threadIdx.x & 63, ty = threadIdx.x >> 6;
  const int n0 = bx * 64, k0 = by * 64;
#pragma unroll
  for (int i = 0; i < 16; ++i) {
    int k = ty + i * 4;
    tile[k][tx] = W[(size_t)(k0 + k) * Ec + n0 + tx];
  }
  __syncthreads();
#pragma unroll
  for (int i = 0; i < 16; ++i) {
    int n = ty + i * 4;
    Wt[(size_t)(n0 + n) * Ec + k0 + tx] = (half_t)tile[tx][n];
  }
}

// ---------------- fused projection GEMM: xh(8192x1024) @ Wcat(5120x1024)^T ----------------
// group g = col/1024: 0=q(BHSD,scale) 1=k(BHSD) 2=v(BHDS) 3=kg(BHSD) 4=vg(BHDS)
__global__ __launch_bounds__(256) void gemm_proj(const half_t* __restrict__ A,
                                                 const half_t* __restrict__ Bt,
                                                 const float* __restrict__ bq,
                                                 const float* __restrict__ bk,
                                                 const float* __restrict__ bv,
                                                 const float* __restrict__ bkg,
                                                 const float* __restrict__ bvg,
                                                 half_t* __restrict__ qh, half_t* __restrict__ kh,
                                                 half_t* __restrict__ vt, half_t* __restrict__ kgh,
                                                 half_t* __restrict__ vgt) {
  __shared__ __align__(16) half_t Ash[128 * 32];
  __shared__ __align__(16) half_t Bsh[128 * 32];
  const int tid = threadIdx.x;
  const int wv = tid >> 6, lane = tid & 63;
  const int mr = lane & 15, qd = lane >> 4;
  const int wv_m = wv >> 1, wv_n = wv & 1;
  const int col0 = blockIdx.x * 128;
  const int row0 = blockIdx.y * 128;
  const int g = col0 >> 10;
  const float* bptr = (g == 0) ? bq : (g == 1) ? bk : (g == 2) ? bv : (g == 3) ? bkg : bvg;

  f4 acc[4][4] = {};

  for (int k0 = 0; k0 < Ec; k0 += 32) {
#pragma unroll
    for (int i = 0; i < 2; ++i) {
      int slot = wv * 128 + i * 64 + lane;
      int r = slot >> 2;
      int kc = (slot & 3) ^ ((r >> 1) & 3);  // parity-spread swizzle (2-way max)
      gl_lds16(A + (size_t)(row0 + r) * Ec + k0 + kc * 8, Ash + (size_t)(wv * 128 + i * 64) * 8);
      gl_lds16(Bt + (size_t)(col0 + r) * Ec + k0 + kc * 8, Bsh + (size_t)(wv * 128 + i * 64) * 8);
    }
    __syncthreads();
    h8 af[4], bf[4];
#pragma unroll
    for (int mt = 0; mt < 4; ++mt) {
      int r = wv_m * 64 + mt * 16 + mr;
      af[mt] = *(const h8*)(Ash + (size_t)((r << 2) | (qd ^ ((r >> 1) & 3))) * 8);
    }
#pragma unroll
    for (int nt = 0; nt < 4; ++nt) {
      int r = wv_n * 64 + nt * 16 + mr;
      bf[nt] = *(const h8*)(Bsh + (size_t)((r << 2) | (qd ^ ((r >> 1) & 3))) * 8);
    }
#pragma unroll
    for (int mt = 0; mt < 4; ++mt)
#pragma unroll
      for (int nt = 0; nt < 4; ++nt)
        acc[mt][nt] = mfma16(af[mt], bf[nt], acc[mt][nt]);
    __syncthreads();
  }

  const float scale = (g == 0) ? QSCALE : 1.0f;
#pragma unroll
  for (int mt = 0; mt < 4; ++mt) {
#pragma unroll
    for (int nt = 0; nt < 4; ++nt) {
      const int C = col0 + wv_n * 64 + nt * 16 + mr;
      const int c1 = C & 1023, hh = c1 >> 6, d = c1 & 63;
      const float bval = bptr[c1];
      const int Rbase = row0 + wv_m * 64 + mt * 16 + qd * 4;
      f4 a = acc[mt][nt];
      if (g == 2 || g == 4) {  // transposed (B,H,D,S)
        half_t* O = (g == 2) ? vt : vgt;
        int b = Rbase >> 12, s = Rbase & 4095;
        h4 pk;
#pragma unroll
        for (int r = 0; r < 4; ++r) pk[r] = (half_t)(a[r] + bval);
        *(h4*)(O + ((size_t)(b * Hc + hh) * Dc + d) * Sc + s) = pk;
      } else {                 // (B,H,S,D)
        half_t* O = (g == 0) ? qh : (g == 1) ? kh : kgh;
#pragma unroll
        for (int r = 0; r < 4; ++r) {
          int R = Rbase + r;
          int b = R >> 12, s = R & 4095;
          O[((size_t)(b * Hc + hh) * Sc + s) * Dc + d] = (half_t)((a[r] + bval) * scale);
        }
      }
    }
  }
}

// ---------------- qg projection: 128 gathered rows (s<G per batch) ----------------
__global__ __launch_bounds__(256) void gemm_qg(const half_t* __restrict__ A,
                                               const half_t* __restrict__ Bt,
                                               const float* __restrict__ bqg,
                                               half_t* __restrict__ qgh) {
  __shared__ __align__(16) half_t Ash[128 * 32];
  __shared__ __align__(16) half_t Bsh[128 * 32];
  const int tid = threadIdx.x;
  const int wv = tid >> 6, lane = tid & 63;
  const int mr = lane & 15, qd = lane >> 4;
  const int wv_m = wv >> 1, wv_n = wv & 1;
  const int col0 = blockIdx.x * 128;

  f4 acc[4][4] = {};

  for (int k0 = 0; k0 < Ec; k0 += 32) {
#pragma unroll
    for (int i = 0; i < 2; ++i) {
      int slot = wv * 128 + i * 64 + lane;
      int r = slot >> 2;
      int grow = (r < 64) ? r : (4032 + r);  // b0: rows 0..63; b1: rows 4096..4159
      int kc = (slot & 3) ^ ((r >> 1) & 3);
      gl_lds16(A + (size_t)grow * Ec + k0 + kc * 8, Ash + (size_t)(wv * 128 + i * 64) * 8);
      gl_lds16(Bt + (size_t)(col0 + r) * Ec + k0 + kc * 8, Bsh + (size_t)(wv * 128 + i * 64) * 8);
    }
    __syncthreads();
    h8 af[4], bf[4];
#pragma unroll
    for (int mt = 0; mt < 4; ++mt) {
      int r = wv_m * 64 + mt * 16 + mr;
      af[mt] = *(const h8*)(Ash + (size_t)((r << 2) | (qd ^ ((r >> 1) & 3))) * 8);
    }
#pragma unroll
    for (int nt = 0; nt < 4; ++nt) {
      int r = wv_n * 64 + nt * 16 + mr;
      bf[nt] = *(const h8*)(Bsh + (size_t)((r << 2) | (qd ^ ((r >> 1) & 3))) * 8);
    }
#pragma unroll
    for (int mt = 0; mt < 4; ++mt)
#pragma unroll
      for (int nt = 0; nt < 4; ++nt)
        acc[mt][nt] = mfma16(af[mt], bf[nt], acc[mt][nt]);
    __syncthreads();
  }

#pragma unroll
  for (int mt = 0; mt < 4; ++mt) {
#pragma unroll
    for (int nt = 0; nt < 4; ++nt) {
      const int C = col0 + wv_n * 64 + nt * 16 + mr;
      const int hh = C >> 6, d = C & 63;
      const float bval = bqg[C];
      const int Rbase = wv_m * 64 + mt * 16 + qd * 4;
      f4 a = acc[mt][nt];
#pragma unroll
      for (int r = 0; r < 4; ++r) {
        int rr = Rbase + r;
        int b = rr >> 6, s = rr & 63;
        qgh[((size_t)(b * Hc + hh) * Gc + s) * Dc + d] = (half_t)((a[r] + bval) * QSCALE);
      }
    }
  }
}

// ---------------- output GEMM: ctx(8192x1024) @ WtO^T + bo -> fp32 ----------------
__global__ __launch_bounds__(256) void gemm_out(const half_t* __restrict__ A,
                                                const half_t* __restrict__ Bt,
                                                const float* __restrict__ bias,
                                                float* __restrict__ O) {
  __shared__ __align__(16) half_t Ash[128 * 32];
  __shared__ __align__(16) half_t Bsh[128 * 32];
  const int tid = threadIdx.x;
  const int wv = tid >> 6, lane = tid & 63;
  const int mr = lane & 15, qd = lane >> 4;
  const int wv_m = wv >> 1, wv_n = wv & 1;
  const int col0 = blockIdx.x * 128;
  const int row0 = blockIdx.y * 128;

  f4 acc[4][4] = {};

  for (int k0 = 0; k0 < Ec; k0 += 32) {
#pragma unroll
    for (int i = 0; i < 2; ++i) {
      int slot = wv * 128 + i * 64 + lane;
      int r = slot >> 2;
      int kc = (slot & 3) ^ ((r >> 1) & 3);
      gl_lds16(A + (size_t)(row0 + r) * Ec + k0 + kc * 8, Ash + (size_t)(wv * 128 + i * 64) * 8);
      gl_lds16(Bt + (size_t)(col0 + r) * Ec + k0 + kc * 8, Bsh + (size_t)(wv * 128 + i * 64) * 8);
    }
    __syncthreads();
    h8 af[4], bf[4];
#pragma unroll
    for (int mt = 0; mt < 4; ++mt) {
      int r = wv_m * 64 + mt * 16 + mr;
      af[mt] = *(const h8*)(Ash + (size_t)((r << 2) | (qd ^ ((r >> 1) & 3))) * 8);
    }
#pragma unroll
    for (int nt = 0; nt < 4; ++nt) {
      int r = wv_n * 64 + nt * 16 + mr;
      bf[nt] = *(const h8*)(Bsh + (size_t)((r << 2) | (qd ^ ((r >> 1) & 3))) * 8);
    }
#pragma unroll
    for (int mt = 0; mt < 4; ++mt)
#pragma unroll
      for (int nt = 0; nt < 4; ++nt)
        acc[mt][nt] = mfma16(af[mt], bf[nt], acc[mt][nt]);
    __syncthreads();
  }

#pragma unroll
  for (int mt = 0; mt < 4; ++mt) {
#pragma unroll
    for (int nt = 0; nt < 4; ++nt) {
      const int C = col0 + wv_n * 64 + nt * 16 + mr;
      const float bval = bias[C];
      const int Rbase = row0 + wv_m * 64 + mt * 16 + qd * 4;
      f4 a = acc[mt][nt];
#pragma unroll
      for (int r = 0; r < 4; ++r)
        O[(size_t)(Rbase + r) * Ec + C] = a[r] + bval;
    }
  }
}

// ---------------- windowed + global-key attention (flash-style, LDS-staged) ----------------
__global__ __launch_bounds__(256) void win_attn(const half_t* __restrict__ qh,
                                                const half_t* __restrict__ kh,
                                                const half_t* __restrict__ vt,
                                                half_t* __restrict__ ctx) {
  constexpr int PST = 88;
  __shared__ __align__(16) half_t Kb[2][64 * 64];
  __shared__ __align__(16) half_t Vb[2][64 * 64];
  __shared__ __align__(16) half_t Pl[4][16 * PST];
  const int bid = blockIdx.x;
  const int qc = bid & 15, h = (bid >> 4) & 15, b = bid >> 8;
  const int qs = qc << 8;
  const int tid = threadIdx.x, wv = tid >> 6, lane = tid & 63;
  const int mr = lane & 15, qd = lane >> 4;
  const int qw = qs + wv * 64;
  const size_t bh = (size_t)(b * Hc + h);
  const half_t* qb = qh + bh * Sc * Dc;
  const half_t* kb = kh + bh * Sc * Dc;
  const half_t* vb = vt + bh * Dc * Sc;
  half_t* Pw = &Pl[wv][0];

  h8 qf[4][2];
#pragma unroll
  for (int qt = 0; qt < 4; ++qt) {
    const half_t* qrow = qb + (size_t)(qw + qt * 16 + mr) * Dc;
    qf[qt][0] = *(const h8*)(qrow + qd * 8);
    qf[qt][1] = *(const h8*)(qrow + 32 + qd * 8);
  }

  int tiles[14];
  int nT = 0;
  tiles[nT++] = 0;
  {
    int lo = qs - Wc; if (lo < Gc) lo = Gc;
    int hi = qs + 448; if (hi > Sc - 64) hi = Sc - 64;
    for (int kp0 = lo; kp0 <= hi; kp0 += 64) tiles[nT++] = kp0;
  }

  auto stage = [&](int kp0, int bi) {
#pragma unroll
    for (int i = 0; i < 2; ++i) {
      const int seg = wv * 2 + i;
      const int s = seg * 64 + lane;
      const int r = s >> 3;
      const int kc = (s & 7) ^ (r & 7);
      gl_lds16(kb + (size_t)(kp0 + r) * Dc + kc * 8, &Kb[bi][seg * 512]);
      gl_lds16(vb + (size_t)r * Sc + kp0 + kc * 8, &Vb[bi][seg * 512]);
    }
  };

  float m_run[4], l_run[4];
  f4 acc[4][4] = {};
#pragma unroll
  for (int qt = 0; qt < 4; ++qt) { m_run[qt] = -1e30f; l_run[qt] = 0.f; }

  stage(tiles[0], 0);

  for (int t = 0; t < nT; ++t) {
    __syncthreads();
    if (t + 1 < nT) stage(tiles[t + 1], (t + 1) & 1);
    const int kp0 = tiles[t];
    if (t > 0 && (kp0 > qw + 319 || kp0 + 63 < qw - Wc)) continue;

    const half_t* BK = Kb[t & 1];
    const half_t* BV = Vb[t & 1];
    h8 kf[4][2], vf[4][2];
#pragma unroll
    for (int mt = 0; mt < 4; ++mt) {
      const int row = mt * 16 + mr, r7 = row & 7;
      kf[mt][0] = *(const h8*)(BK + (size_t)(row * 8 + (qd ^ r7)) * 8);
      kf[mt][1] = *(const h8*)(BK + (size_t)(row * 8 + ((qd + 4) ^ r7)) * 8);
      vf[mt][0] = *(const h8*)(BV + (size_t)(row * 8 + (qd ^ r7)) * 8);
      vf[mt][1] = *(const h8*)(BV + (size_t)(row * 8 + ((qd + 4) ^ r7)) * 8);
    }
    const bool nomask = (t == 0) || (kp0 >= qw - 193 && kp0 <= qw + 193);

#pragma unroll
    for (int qt = 0; qt < 4; ++qt) {
      f4 sa[4];
#pragma unroll
      for (int mt = 0; mt < 4; ++mt) {
        f4 s = {};
        s = mfma16(kf[mt][0], qf[qt][0], s);
        s = mfma16(kf[mt][1], qf[qt][1], s);
        sa[mt] = s;
      }
      const int q = qw + qt * 16 + mr;
      if (!nomask) {
#pragma unroll
        for (int mt = 0; mt < 4; ++mt)
#pragma unroll
          for (int r = 0; r < 4; ++r) {
            const int kp = kp0 + mt * 16 + qd * 4 + r;
            if (kp < q - Wc || kp > q + Wc) sa[mt][r] = NEGV;
          }
      }
      float tm = -1e30f;
#pragma unroll
      for (int mt = 0; mt < 4; ++mt)
#pragma unroll
        for (int r = 0; r < 4; ++r) tm = fmaxf(tm, sa[mt][r]);
      tm = fmaxf(tm, __shfl_xor(tm, 16));
      tm = fmaxf(tm, __shfl_xor(tm, 32));
      const float mnew = fmaxf(m_run[qt], tm);
      const float alpha = __expf(m_run[qt] - mnew);
      m_run[qt] = mnew;
      float psum = 0.0f;
#pragma unroll
      for (int mt = 0; mt < 4; ++mt) {
        h4 pk;
#pragma unroll
        for (int r = 0; r < 4; ++r) {
          const float p = __expf(sa[mt][r] - mnew);
          psum += p;
          pk[r] = (half_t)p;
        }
        *(h4*)(Pw + mr * PST + mt * 16 + qd * 4) = pk;
      }
      psum += __shfl_xor(psum, 16);
      psum += __shfl_xor(psum, 32);
      l_run[qt] = l_run[qt] * alpha + psum;
#pragma unroll
      for (int mt = 0; mt < 4; ++mt)
#pragma unroll
        for (int r = 0; r < 4; ++r) acc[qt][mt][r] *= alpha;
      const h8 p0 = *(const h8*)(Pw + mr * PST + qd * 8);
      const h8 p1 = *(const h8*)(Pw + mr * PST + 32 + qd * 8);
#pragma unroll
      for (int mt = 0; mt < 4; ++mt) {
        acc[qt][mt] = mfma16(vf[mt][0], p0, acc[qt][mt]);
        acc[qt][mt] = mfma16(vf[mt][1], p1, acc[qt][mt]);
      }
    }
  }

#pragma unroll
  for (int qt = 0; qt < 4; ++qt) {
    const float inv = 1.0f / l_run[qt];
    const int q = qw + qt * 16 + mr;
    half_t* crow = ctx + ((size_t)(b * Sc) + q) * Ec + h * Dc;
#pragma unroll
    for (int mt = 0; mt < 4; ++mt) {
      h4 pk;
#pragma unroll
      for (int r = 0; r < 4; ++r) pk[r] = (half_t)(acc[qt][mt][r] * inv);
      *(h4*)(crow + mt * 16 + qd * 4) = pk;
    }
  }
}

// ---------------- global-query attention (3 kernels) ----------------

__global__ __launch_bounds__(256) void gq_scores(const half_t* __restrict__ qgh,
                                                 const half_t* __restrict__ kgh,
                                                 float* __restrict__ Sg) {
  const int st = blockIdx.x & 15, h = (blockIdx.x >> 4) & 15, b = blockIdx.x >> 8;
  const int wv = threadIdx.x >> 6, lane = threadIdx.x & 63;
  const int mr = lane & 15, qd = lane >> 4;
  const size_t bh = (size_t)(b * Hc + h);
  const half_t* qb = qgh + bh * Gc * Dc;
  const half_t* kb = kgh + bh * Sc * Dc;
  float* out = Sg + bh * Gc * Sc;

  h8 a0 = *(const h8*)(qb + (size_t)(wv * 16 + mr) * Dc + qd * 8);
  h8 a1 = *(const h8*)(qb + (size_t)(wv * 16 + mr) * Dc + 32 + qd * 8);
#pragma unroll 4
  for (int nt = 0; nt < 16; ++nt) {
    int s = st * 256 + nt * 16 + mr;
    h8 b0 = *(const h8*)(kb + (size_t)s * Dc + qd * 8);
    h8 b1 = *(const h8*)(kb + (size_t)s * Dc + 32 + qd * 8);
    f4 scv = {};
    scv = mfma16(a0, b0, scv);
    scv = mfma16(a1, b1, scv);
#pragma unroll
    for (int r = 0; r < 4; ++r)
      out[(size_t)(wv * 16 + qd * 4 + r) * Sc + st * 256 + nt * 16 + mr] = scv[r];
  }
}

__global__ __launch_bounds__(256) void gq_softmax(const float* __restrict__ Sg,
                                                  half_t* __restrict__ Pg) {
  const int row = blockIdx.x;
  const float* src = Sg + (size_t)row * Sc;
  half_t* dst = Pg + (size_t)row * Sc;
  const int t = threadIdx.x;
  __shared__ float red[4], reds[4];
  float mx = -1e30f;
  for (int i = t; i < Sc; i += 256) mx = fmaxf(mx, src[i]);
#pragma unroll
  for (int o = 1; o < 64; o <<= 1) mx = fmaxf(mx, __shfl_xor(mx, o));
  if ((t & 63) == 0) red[t >> 6] = mx;
  __syncthreads();
  mx = fmaxf(fmaxf(red[0], red[1]), fmaxf(red[2], red[3]));
  float pv[16];
  float sum = 0.f;
  for (int i = t, j = 0; i < Sc; i += 256, ++j) {
    pv[j] = __expf(src[i] - mx);
    sum += pv[j];
  }
#pragma unroll
  for (int o = 1; o < 64; o <<= 1) sum += __shfl_xor(sum, o);
  if ((t & 63) == 0) reds[t >> 6] = sum;
  __syncthreads();
  sum = reds[0] + reds[1] + reds[2] + reds[3];
  float inv = 1.0f / sum;
  for (int i = t, j = 0; i < Sc; i += 256, ++j) dst[i] = (half_t)(pv[j] * inv);
}

__global__ __launch_bounds__(256) void gq_pv(const half_t* __restrict__ Pg,
                                             const half_t* __restrict__ vgt,
                                             half_t* __restrict__ ctx) {
  const int ds = blockIdx.x & 3, h = (blockIdx.x >> 2) & 15, b = blockIdx.x >> 6;
  const int wv = threadIdx.x >> 6, lane = threadIdx.x & 63;
  const int mr = lane & 15, qd = lane >> 4;
  const size_t bh = (size_t)(b * Hc + h);
  const half_t* pb = Pg + bh * Gc * Sc;
  const int d = ds * 16 + mr;
  const half_t* vb = vgt + (bh * Dc + d) * Sc;
  f4 o = {};
  for (int ch = 0; ch < 128; ++ch) {
    h8 af = *(const h8*)(pb + (size_t)(wv * 16 + mr) * Sc + ch * 32 + qd * 8);
    h8 bf = *(const h8*)(vb + ch * 32 + qd * 8);
    o = mfma16(af, bf, o);
  }
#pragma unroll
  for (int r = 0; r < 4; ++r) {
    int g = wv * 16 + qd * 4 + r;
    ctx[(size_t)(b * Sc + g) * Ec + h * Dc + d] = (half_t)o[r];
  }
}

// ---------------- host launch ----------------

extern "C" void kernel_launch(void* const* d_in, const int* in_sizes, int n_in,
                              void* d_out, int out_size, void* d_ws, size_t ws_size,
                              hipStream_t stream) {
  const float* x   = (const float*)d_in[0];
  const float* Wq  = (const float*)d_in[2];
  const float* bq  = (const float*)d_in[3];
  const float* Wk  = (const float*)d_in[4];
  const float* bk  = (const float*)d_in[5];
  const float* Wv  = (const float*)d_in[6];
  const float* bv  = (const float*)d_in[7];
  const float* Wqg = (const float*)d_in[8];
  const float* bqg = (const float*)d_in[9];
  const float* Wkg = (const float*)d_in[10];
  const float* bkg = (const float*)d_in[11];
  const float* Wvg = (const float*)d_in[12];
  const float* bvg = (const float*)d_in[13];
  const float* Wo  = (const float*)d_in[14];
  const float* bo  = (const float*)d_in[15];
  float* out = (float*)d_out;

  char* ws = (char*)d_ws;
  size_t off = 0;
  auto alloc = [&](size_t bytes) {
    void* p = ws + off;
    off = (off + bytes + 255) & ~(size_t)255;
    return p;
  };
  const size_t BSE2 = (size_t)Bc * Sc * Ec * 2;
  const size_t W2 = (size_t)Ec * Ec * 2;
  half_t* xh   = (half_t*)alloc(BSE2);
  half_t* Wcat = (half_t*)alloc(W2 * 5);            // q,k,v,kg,vg transposed f16
  half_t* WtQg = (half_t*)alloc(W2);
  half_t* WtO  = (half_t*)alloc(W2);
  half_t* qh   = (half_t*)alloc(BSE2);              // (B,H,S,D) scaled
  half_t* kh   = (half_t*)alloc(BSE2);              // (B,H,S,D)
  half_t* vt   = (half_t*)alloc(BSE2);              // (B,H,D,S)
  half_t* kgh  = (half_t*)alloc(BSE2);              // (B,H,S,D)
  half_t* vgt  = (half_t*)alloc(BSE2);              // (B,H,D,S)
  half_t* qgh  = (half_t*)alloc((size_t)Bc * Hc * Gc * Dc * 2);
  half_t* ctx  = (half_t*)alloc(BSE2);
  float*  Sg   = (float*)alloc((size_t)Bc * Hc * Gc * Sc * 4);
  half_t* Pg   = (half_t*)alloc((size_t)Bc * Hc * Gc * Sc * 2);
  (void)ws_size; (void)in_sizes; (void)n_in; (void)out_size;

  cvt_x_kernel<<<8192, 256, 0, stream>>>(x, xh);
  wcvt_all<<<dim3(256, 7), 256, 0, stream>>>(Wq, Wk, Wv, Wkg, Wvg, Wqg, Wo, Wcat, WtQg, WtO);

  gemm_proj<<<dim3(40, 64), 256, 0, stream>>>(xh, Wcat, bq, bk, bv, bkg, bvg,
                                              qh, kh, vt, kgh, vgt);
  gemm_qg<<<8, 256, 0, stream>>>(xh, WtQg, bqg, qgh);

  win_attn<<<Bc * Hc * (Sc / 256), 256, 0, stream>>>(qh, kh, vt, ctx);

  gq_scores<<<Bc * Hc * 16, 256, 0, stream>>>(qgh, kgh, Sg);
  gq_softmax<<<Bc * Hc * Gc, 256, 0, stream>>>(Sg, Pg);
  gq_pv<<<Bc * Hc * 4, 256, 0, stream>>>(Pg, vgt, ctx);

  gemm_out<<<dim3(8, 64), 256, 0, stream>>>(ctx, WtO, bo, out);
}